// Round 2
// baseline (161.613 us; speedup 1.0000x reference)
//
#include <hip/hip_runtime.h>
#include <hip/hip_cooperative_groups.h>
#include <stdint.h>

namespace cg = cooperative_groups;

// CandidateFinder: binary-quantize (x>0), exact match on two 32-bit dim
// groups (union), gather first <=64 matching key indices per query, pad -1.
//
// R12 -> R13 post-mortem: scan-side "optimizations" are invisible. Real
// memory work is ~6MB total (~1us at BW); the controllable slice is
// dur_us(63) - timed 268MB poison fill(41) ~= 22us, dominated by the two
// kernel launches + the stream drain between sig and match (match waits for
// ALL sig blocks, then a second launch). R12's 512-thr match also dropped
// occupancy to 2 waves/SIMD (small regression, 63->65).
//
// R13: ONE cooperative kernel (guide-sanctioned grid sync). Phase A: each of
// 256 blocks signs 32 key rows (2 rows/wave, single uint4 store). Query
// ballots issued before the grid barrier so their latency hides under it.
// grid.sync(), then phase B = R11's proven 1024-thr 2q/wave match verbatim.
// Saves one launch + full-stream drain; grid barrier ~1-2us.
//
// wave=64 lanes <-> 64 dims: __ballot(v>0) IS the row's two 32-bit group
// signatures in canonical bit order. Matches emitted in ascending key order
// via ballot+popcount prefix = reference's sort-then-truncate.

#define LSEQ 2048
#define DDIM 64
#define KMAX 64
#define RPW  8    // rows packed per wave in sig kernel (fallback)
#define MQPB 32   // queries per match block (1024 thr, 16 waves, 2 q/wave)

// ---------- Primary: single cooperative kernel ----------
__global__ __launch_bounds__(1024) void coop_kernel(
    const float* __restrict__ query, const float* __restrict__ key,
    uint2* __restrict__ ksig, int* __restrict__ out) {
    __shared__ uint4 sh[LSEQ / 2];      // 16 KB (uint4 = 2 key sigs)

    int lane = threadIdx.x & 63;
    int wave = threadIdx.x >> 6;        // 0..15

    // ---- Phase A: sign this block's 32 key rows (2 rows/wave) ----
    int krow = blockIdx.x * 32 + wave * 2;
    {
        const float* kp = key + (size_t)krow * DDIM + lane;
        float k0 = kp[0], k1 = kp[DDIM];
        unsigned long long km0 = __ballot(k0 > 0.0f);
        unsigned long long km1 = __ballot(k1 > 0.0f);
        if (lane == 0)                   // rows contiguous -> one 16B store
            *(uint4*)(ksig + krow) = make_uint4(
                (unsigned)km0, (unsigned)(km0 >> 32),
                (unsigned)km1, (unsigned)(km1 >> 32));
    }

    // ---- independent: this wave's 2 query sigs (latency hides under sync)
    const int bpb = LSEQ / MQPB;        // 64 blocks per batch
    int b    = blockIdx.x / bpb;
    int qblk = blockIdx.x % bpb;
    int q0 = b * LSEQ + qblk * MQPB + wave * 2;     // global query idx
    const float* qp = query + (size_t)q0 * DDIM + lane;
    float v0 = qp[0], v1 = qp[DDIM];
    unsigned long long qm0 = __ballot(v0 > 0.0f);
    unsigned long long qm1 = __ballot(v1 > 0.0f);

    __threadfence();                    // ksig visible device-wide
    cg::this_grid().sync();

    // ---- Phase B: stage batch-b sig table, scan 2 q/wave (R11 verbatim)
    const uint4* gt = (const uint4*)(ksig + (size_t)b * LSEQ);
    sh[threadIdx.x] = gt[threadIdx.x];  // 1024 x 16B = whole 16KB table
    __syncthreads();

    unsigned long long below = (1ull << lane) - 1ull;
    const uint2* ks2 = (const uint2*)sh;
    for (int t = 0; t < 2; ++t) {
        unsigned long long qm = t ? qm1 : qm0;
        unsigned qa = (unsigned)qm, qg = (unsigned)(qm >> 32);
        int* ob = out + (size_t)(q0 + t) * KMAX;

        // fast path: fully branchless, 16 ds_read_b128 back-to-back
        unsigned long long acc = 0;
        int cnt = 0;
#pragma unroll
        for (int i = 0; i < LSEQ / 128; ++i) {      // 16 iters, 128 keys
            uint4 kv = sh[i * 64 + lane];
            bool mA = (kv.x == qa) | (kv.y == qg);  // key 2*(i*64+lane)
            bool mB = (kv.z == qa) | (kv.w == qg);  // key 2*(i*64+lane)+1
            unsigned long long s;
            s = __ballot(mA); acc |= s; cnt += __popcll(s);
            s = __ballot(mB); acc |= s; cnt += __popcll(s);
        }

        if (acc != 0) {                             // wave-uniform, p~2^-26:
            // exact ordered emit (ascending key idx = sort-then-truncate)
            int c2 = 0;
            for (int c = 0; c < LSEQ / 64; ++c) {
                uint2 kv = ks2[c * 64 + lane];
                bool m = (kv.x == qa) || (kv.y == qg);
                unsigned long long mask = __ballot(m);
                if (m) {
                    int pos = c2 + __popcll(mask & below);
                    if (pos < KMAX) ob[pos] = c * 64 + lane;
                }
                c2 += __popcll(mask);
            }
        }
        // pad remaining slots with -1 (64 lanes == KMAX; disjoint vs matches)
        if (lane >= cnt) ob[lane] = -1;
    }
}

// ---------- Fallback A: two-kernel path (R11, proven 63.0us) ----------
__global__ __launch_bounds__(256) void sig_kernel(
    const float* __restrict__ key, uint2* __restrict__ ksig, int nrows) {
    int wid  = (int)((blockIdx.x * blockDim.x + threadIdx.x) >> 6);
    int lane = threadIdx.x & 63;
    int row0 = wid * RPW;
    if (row0 >= nrows) return;                      // wave-uniform
    const float* base = key + (size_t)row0 * DDIM + lane;
    float v[RPW];
#pragma unroll
    for (int u = 0; u < RPW; ++u)
        v[u] = base[(size_t)u * DDIM];
    unsigned long long m[RPW];
#pragma unroll
    for (int u = 0; u < RPW; ++u)
        m[u] = __ballot(v[u] > 0.0f);
    if (lane == 0) {
#pragma unroll
        for (int u = 0; u < RPW; ++u)
            ksig[row0 + u] = make_uint2((unsigned)m[u], (unsigned)(m[u] >> 32));
    }
}

__global__ __launch_bounds__(1024) void match_kernel(
    const float* __restrict__ query, const uint2* __restrict__ ksig,
    int* __restrict__ out) {
    __shared__ uint4 sh[LSEQ / 2];      // 16 KB

    const int bpb = LSEQ / MQPB;        // 64 blocks per batch
    int b    = blockIdx.x / bpb;
    int qblk = blockIdx.x % bpb;
    int lane = threadIdx.x & 63;
    int wave = threadIdx.x >> 6;

    const uint4* gt = (const uint4*)(ksig + (size_t)b * LSEQ);
    sh[threadIdx.x] = gt[threadIdx.x];

    int q0 = b * LSEQ + qblk * MQPB + wave * 2;
    const float* qp = query + (size_t)q0 * DDIM + lane;
    float v0 = qp[0], v1 = qp[DDIM];
    unsigned long long qm0 = __ballot(v0 > 0.0f);
    unsigned long long qm1 = __ballot(v1 > 0.0f);

    __syncthreads();

    unsigned long long below = (1ull << lane) - 1ull;
    const uint2* ks2 = (const uint2*)sh;
    for (int t = 0; t < 2; ++t) {
        unsigned long long qm = t ? qm1 : qm0;
        unsigned qa = (unsigned)qm, qg = (unsigned)(qm >> 32);
        int* ob = out + (size_t)(q0 + t) * KMAX;
        unsigned long long acc = 0;
        int cnt = 0;
#pragma unroll
        for (int i = 0; i < LSEQ / 128; ++i) {
            uint4 kv = sh[i * 64 + lane];
            bool mA = (kv.x == qa) | (kv.y == qg);
            bool mB = (kv.z == qa) | (kv.w == qg);
            unsigned long long s;
            s = __ballot(mA); acc |= s; cnt += __popcll(s);
            s = __ballot(mB); acc |= s; cnt += __popcll(s);
        }
        if (acc != 0) {
            int c2 = 0;
            for (int c = 0; c < LSEQ / 64; ++c) {
                uint2 kv = ks2[c * 64 + lane];
                bool m = (kv.x == qa) || (kv.y == qg);
                unsigned long long mask = __ballot(m);
                if (m) {
                    int pos = c2 + __popcll(mask & below);
                    if (pos < KMAX) ob[pos] = c * 64 + lane;
                }
                c2 += __popcll(mask);
            }
        }
        if (lane >= cnt) ob[lane] = -1;
    }
}

// ---------- Fallback B (ws too small): R5's fused kernel ----------
#define QPB  32
#define NW   16
#define GROUP 32
__global__ __launch_bounds__(1024) void fused_kernel(
    const float* __restrict__ query, const float* __restrict__ key,
    int* __restrict__ out) {
    __shared__ uint2 ks[LSEQ];
    const int bpb  = LSEQ / QPB;
    int b    = blockIdx.x / bpb;
    int qblk = blockIdx.x % bpb;
    int lane = threadIdx.x & 63;
    int wave = threadIdx.x >> 6;
    const float* kb = key + (size_t)b * LSEQ * DDIM;
    for (int g = 0; g < LSEQ / NW / GROUP; ++g) {
        float v[GROUP];
#pragma unroll
        for (int u = 0; u < GROUP; ++u)
            v[u] = kb[(size_t)(g * (NW * GROUP) + u * NW + wave) * DDIM + lane];
        unsigned long long m[GROUP];
#pragma unroll
        for (int u = 0; u < GROUP; ++u) m[u] = __ballot(v[u] > 0.0f);
        if (lane == 0) {
#pragma unroll
            for (int u = 0; u < GROUP; ++u)
                ks[g * (NW * GROUP) + u * NW + wave] =
                    make_uint2((unsigned)m[u], (unsigned)(m[u] >> 32));
        }
    }
    const float* qb = query + ((size_t)b * LSEQ + (size_t)qblk * QPB) * DDIM;
    int q0 = wave * 2;
    float v0 = qb[(size_t)q0 * DDIM + lane];
    float v1 = qb[(size_t)(q0 + 1) * DDIM + lane];
    unsigned long long m0 = __ballot(v0 > 0.0f);
    unsigned long long m1 = __ballot(v1 > 0.0f);
    __syncthreads();
    unsigned long long below = (1ull << lane) - 1ull;
    for (int t = 0; t < 2; ++t) {
        unsigned long long qm = t ? m1 : m0;
        unsigned q1 = (unsigned)qm, q2 = (unsigned)(qm >> 32);
        int* obase = out + ((size_t)b * LSEQ + (size_t)qblk * QPB + q0 + t) * KMAX;
        unsigned long long acc = 0;
        int cnt = 0;
#pragma unroll
        for (int c = 0; c < LSEQ / 64; ++c) {
            uint2 kv = ks[c * 64 + lane];
            bool m = (kv.x == q1) || (kv.y == q2);
            unsigned long long mask = __ballot(m);
            acc |= mask; cnt += __popcll(mask);
        }
        if (acc != 0) {
            int c2 = 0;
            for (int c = 0; c < LSEQ / 64; ++c) {
                uint2 kv = ks[c * 64 + lane];
                bool m = (kv.x == q1) || (kv.y == q2);
                unsigned long long mask = __ballot(m);
                if (m) {
                    int pos = c2 + __popcll(mask & below);
                    if (pos < KMAX) obase[pos] = c * 64 + lane;
                }
                c2 += __popcll(mask);
            }
        }
        if (lane >= cnt) obase[lane] = -1;
    }
}

extern "C" void kernel_launch(void* const* d_in, const int* in_sizes, int n_in,
                              void* d_out, int out_size, void* d_ws, size_t ws_size,
                              hipStream_t stream) {
    const float* q = (const float*)d_in[0];
    const float* k = (const float*)d_in[1];
    // d_in[2] = head_idx, unused (inputs are already per-head)
    int* out = (int*)d_out;

    int total = in_sizes[0];             // B * L * D
    int B = total / (LSEQ * DDIM);       // = 4
    int nrows = B * LSEQ;                // 8192

    if (ws_size >= (size_t)nrows * sizeof(uint2)) {
        uint2* ksig = (uint2*)d_ws;
        void* args[] = {(void*)&q, (void*)&k, (void*)&ksig, (void*)&out};
        hipError_t e = hipLaunchCooperativeKernel(
            (const void*)coop_kernel, dim3(nrows / MQPB), dim3(1024),
            args, 0, stream);
        if (e != hipSuccess) {           // coop unsupported under capture?
            sig_kernel<<<nrows / RPW * 64 / 256, 256, 0, stream>>>(k, ksig, nrows);
            match_kernel<<<nrows / MQPB, 1024, 0, stream>>>(q, ksig, out);
        }
    } else {
        fused_kernel<<<B * (LSEQ / QPB), 1024, 0, stream>>>(q, k, out);
    }
}

// Round 3
// 62.894 us; speedup vs baseline: 2.5696x; 2.5696x over previous
//
#include <hip/hip_runtime.h>
#include <stdint.h>

// CandidateFinder: binary-quantize (x>0), exact match on two 32-bit dim
// groups (union), gather first <=64 matching key indices per query, pad -1.
//
// R13 post-mortem: cooperative grid.sync costs ~85us on MI355X (256 blocks,
// spin via device-scope flags across 8 non-coherent XCD L2s) -- coop_kernel
// measured 90-97us at 0.6% HBM. Grid sync is permanently off the table.
// Counters confirm total real traffic ~4.6MB (~1us at BW); measured 63us =
// 41us harness ws-poison fill + ~10us harness reset nodes + 2 kernel nodes.
//
// R14: proven R11 two-node structure, restored, plus the last body slack:
//  (a) sig node signs BOTH keys and queries (512 blocks; same code, rows
//      0..8191=keys, 8192..16383=queries). match reads 8B qsig per wave
//      instead of 512B raw query: -2MB HBM + removes two dependent
//      ~900-cyc load+ballot chains from match's critical path.
//  (b) match common path (no match, p~2^-26/wave): no popcount bookkeeping,
//      and the 64x -1 pad is written as 16 int4 stores instead of 64 scalar.
//
// wave=64 lanes <-> 64 dims: __ballot(v>0) IS the row's two 32-bit group
// signatures in canonical bit order. Matches emitted in ascending key order
// via ballot+popcount prefix = reference's sort-then-truncate.

#define LSEQ 2048
#define DDIM 64
#define KMAX 64
#define RPW  8    // rows packed per wave in sig kernel
#define MQPB 32   // queries per match block (1024 thr, 16 waves, 2 q/wave)

// Phase 1: pack sign bits of keys (rows < nrows) and queries (rows >= nrows).
__global__ __launch_bounds__(256) void sig_kernel(
    const float* __restrict__ key, const float* __restrict__ query,
    uint2* __restrict__ ksig, uint2* __restrict__ qsig, int nrows) {
    int wid  = (int)((blockIdx.x * blockDim.x + threadIdx.x) >> 6);
    int lane = threadIdx.x & 63;
    int row0 = wid * RPW;               // over 2*nrows rows
    const float* src;
    uint2* dst;
    if (row0 >= nrows) {                // wave-uniform select
        src = query; dst = qsig; row0 -= nrows;
    } else {
        src = key;   dst = ksig;
    }
    if (row0 >= nrows) return;
    const float* base = src + (size_t)row0 * DDIM + lane;
    float v[RPW];
#pragma unroll
    for (int u = 0; u < RPW; ++u)                   // 8 loads, one BB
        v[u] = base[(size_t)u * DDIM];              // 256B/wave coalesced
    unsigned long long m[RPW];
#pragma unroll
    for (int u = 0; u < RPW; ++u)
        m[u] = __ballot(v[u] > 0.0f);               // branchless, scalar dst
    if (lane == 0) {                                // one exec toggle
#pragma unroll
        for (int u = 0; u < RPW; ++u)               // 64B contiguous
            dst[row0 + u] = make_uint2((unsigned)m[u], (unsigned)(m[u] >> 32));
    }
}

// Phase 2: 256 blocks x 1024 thr; block stages its batch's 16KB key-sig
// table in LDS (one uint4 per thread), then 16 waves scan 2 queries each.
__global__ __launch_bounds__(1024) void match_kernel(
    const uint2* __restrict__ qsig, const uint2* __restrict__ ksig,
    int* __restrict__ out) {
    __shared__ uint4 sh[LSEQ / 2];      // 16 KB (uint4 = 2 key sigs)

    const int bpb = LSEQ / MQPB;        // 64 blocks per batch
    int b    = blockIdx.x / bpb;
    int qblk = blockIdx.x % bpb;
    int lane = threadIdx.x & 63;
    int wave = threadIdx.x >> 6;

    // stage: 1024 threads x 16B = whole table, one global round-trip
    const uint4* gt = (const uint4*)(ksig + (size_t)b * LSEQ);
    sh[threadIdx.x] = gt[threadIdx.x];

    // this wave's 2 query signatures: one 8B broadcast load each
    int q0 = b * LSEQ + qblk * MQPB + wave * 2;     // global query idx
    uint2 qs0 = qsig[q0];
    uint2 qs1 = qsig[q0 + 1];

    __syncthreads();

    unsigned long long below = (1ull << lane) - 1ull;
    const uint2* ks2 = (const uint2*)sh;
#pragma unroll
    for (int t = 0; t < 2; ++t) {
        unsigned qa = t ? qs1.x : qs0.x;
        unsigned qg = t ? qs1.y : qs0.y;
        int* ob = out + (size_t)(q0 + t) * KMAX;

        // fast path: pure match detector, 16 ds_read_b128 + 32 ballots,
        // no popcounts
        unsigned long long acc = 0;
#pragma unroll
        for (int i = 0; i < LSEQ / 128; ++i) {      // 16 iters, 128 keys
            uint4 kv = sh[i * 64 + lane];
            bool mA = (kv.x == qa) | (kv.y == qg);  // key 2*(i*64+lane)
            bool mB = (kv.z == qa) | (kv.w == qg);  // key 2*(i*64+lane)+1
            acc |= __ballot(mA) | __ballot(mB);
        }

        if (acc != 0) {                             // wave-uniform, p~2^-26:
            // exact ordered emit (ascending key idx = sort-then-truncate)
            int c2 = 0;
            for (int c = 0; c < LSEQ / 64; ++c) {
                uint2 kv = ks2[c * 64 + lane];
                bool m = (kv.x == qa) || (kv.y == qg);
                unsigned long long mask = __ballot(m);
                if (m) {
                    int pos = c2 + __popcll(mask & below);
                    if (pos < KMAX) ob[pos] = c * 64 + lane;
                }
                c2 += __popcll(mask);
            }
            if (lane >= c2) ob[lane] = -1;          // pad (disjoint vs matches)
        } else {
            // common path: all 64 slots = -1, vectorized 16B stores
            if (lane < 16)
                ((int4*)ob)[lane] = make_int4(-1, -1, -1, -1);
        }
    }
}

// Fallback (ws too small): R5's proven self-contained fused kernel.
#define QPB  32
#define NW   16
#define GROUP 32
__global__ __launch_bounds__(1024) void fused_kernel(
    const float* __restrict__ query, const float* __restrict__ key,
    int* __restrict__ out) {
    __shared__ uint2 ks[LSEQ];
    const int bpb  = LSEQ / QPB;
    int b    = blockIdx.x / bpb;
    int qblk = blockIdx.x % bpb;
    int lane = threadIdx.x & 63;
    int wave = threadIdx.x >> 6;
    const float* kb = key + (size_t)b * LSEQ * DDIM;
    for (int g = 0; g < LSEQ / NW / GROUP; ++g) {
        float v[GROUP];
#pragma unroll
        for (int u = 0; u < GROUP; ++u)
            v[u] = kb[(size_t)(g * (NW * GROUP) + u * NW + wave) * DDIM + lane];
        unsigned long long m[GROUP];
#pragma unroll
        for (int u = 0; u < GROUP; ++u) m[u] = __ballot(v[u] > 0.0f);
        if (lane == 0) {
#pragma unroll
            for (int u = 0; u < GROUP; ++u)
                ks[g * (NW * GROUP) + u * NW + wave] =
                    make_uint2((unsigned)m[u], (unsigned)(m[u] >> 32));
        }
    }
    const float* qb = query + ((size_t)b * LSEQ + (size_t)qblk * QPB) * DDIM;
    int q0 = wave * 2;
    float v0 = qb[(size_t)q0 * DDIM + lane];
    float v1 = qb[(size_t)(q0 + 1) * DDIM + lane];
    unsigned long long m0 = __ballot(v0 > 0.0f);
    unsigned long long m1 = __ballot(v1 > 0.0f);
    __syncthreads();
    unsigned long long below = (1ull << lane) - 1ull;
    for (int t = 0; t < 2; ++t) {
        unsigned long long qm = t ? m1 : m0;
        unsigned q1 = (unsigned)qm, q2 = (unsigned)(qm >> 32);
        int* obase = out + ((size_t)b * LSEQ + (size_t)qblk * QPB + q0 + t) * KMAX;
        unsigned long long acc = 0;
        int cnt = 0;
#pragma unroll
        for (int c = 0; c < LSEQ / 64; ++c) {
            uint2 kv = ks[c * 64 + lane];
            bool m = (kv.x == q1) || (kv.y == q2);
            unsigned long long mask = __ballot(m);
            acc |= mask; cnt += __popcll(mask);
        }
        if (acc != 0) {
            int c2 = 0;
            for (int c = 0; c < LSEQ / 64; ++c) {
                uint2 kv = ks[c * 64 + lane];
                bool m = (kv.x == q1) || (kv.y == q2);
                unsigned long long mask = __ballot(m);
                if (m) {
                    int pos = c2 + __popcll(mask & below);
                    if (pos < KMAX) obase[pos] = c * 64 + lane;
                }
                c2 += __popcll(mask);
            }
        }
        if (lane >= cnt) obase[lane] = -1;
    }
}

extern "C" void kernel_launch(void* const* d_in, const int* in_sizes, int n_in,
                              void* d_out, int out_size, void* d_ws, size_t ws_size,
                              hipStream_t stream) {
    const float* q = (const float*)d_in[0];
    const float* k = (const float*)d_in[1];
    // d_in[2] = head_idx, unused (inputs are already per-head)
    int* out = (int*)d_out;

    int total = in_sizes[0];             // B * L * D
    int B = total / (LSEQ * DDIM);       // = 4
    int nrows = B * LSEQ;                // 8192

    if (ws_size >= (size_t)(2 * nrows) * sizeof(uint2)) {   // 128 KB
        uint2* ksig = (uint2*)d_ws;
        uint2* qsig = ksig + nrows;
        int nblk = (2 * nrows) / (RPW * 4);                 // 512 blocks
        sig_kernel<<<nblk, 256, 0, stream>>>(k, q, ksig, qsig, nrows);
        match_kernel<<<nrows / MQPB, 1024, 0, stream>>>(qsig, ksig, out);
    } else {
        fused_kernel<<<B * (LSEQ / QPB), 1024, 0, stream>>>(q, k, out);
    }
}